// Round 4
// baseline (549.997 us; speedup 1.0000x reference)
//
#include <hip/hip_runtime.h>
#include <hip/hip_bf16.h>
#include <math.h>

// Problem constants (from reference setup_inputs)
#define P_ 4
#define B_ 128
#define D_ 512
#define N_ 32768
#define K_ 10
#define TNB 128          // n-tile per block in neg_mfma_kernel
#define NT2 (N_ / TNB)   // 256 tiles per p
#define NG 32            // n-rows per staged group (full-row staging)
#define NGR (TNB / NG)   // 4 groups per block
#define BSTR 520         // padded LDS row stride in shorts (512+8): 260 dwords = 4 mod 32

typedef __attribute__((ext_vector_type(8))) short bf16x8;   // 8 bf16 (4 VGPRs)
typedef __attribute__((ext_vector_type(4))) float f32x4;    // MFMA acc

static __device__ __forceinline__ float block_sum_128(float v, float* sh) {
    const int t = threadIdx.x;
    sh[t] = v; __syncthreads();
    #pragma unroll
    for (int s = 64; s > 0; s >>= 1) { if (t < s) sh[t] += sh[t + s]; __syncthreads(); }
    float r = sh[0]; __syncthreads();
    return r;
}

static __device__ __forceinline__ uint2 pack_bf16x4(float4 v) {
    union { __hip_bfloat162 h; unsigned u; } lo, hi;
    lo.h = __float22bfloat162_rn(make_float2(v.x, v.y));   // RNE
    hi.h = __float22bfloat162_rn(make_float2(v.z, v.w));
    uint2 r; r.x = lo.u; r.y = hi.u;
    return r;
}

// ---------- prep: feature -> bf16 copy (for direct A-frag loads) + fn2 ----------
__global__ __launch_bounds__(256) void prep_kernel(const float* __restrict__ feature,
                                                   unsigned short* __restrict__ Abf,
                                                   float* __restrict__ fn2) {
    const int pb = blockIdx.x;            // 0..P*B-1
    const int t = threadIdx.x;            // 256 threads, 2 consecutive elems each
    const float2 v = *(const float2*)(feature + (size_t)pb * D_ + 2 * t);
    union { __hip_bfloat162 h; unsigned u; } pk;
    pk.h = __float22bfloat162_rn(make_float2(v.x, v.y));
    ((unsigned*)Abf)[(size_t)pb * (D_ / 2) + t] = pk.u;
    __shared__ float sred[256];
    sred[t] = v.x * v.x + v.y * v.y;
    __syncthreads();
    #pragma unroll
    for (int s = 128; s > 0; s >>= 1) { if (t < s) sred[t] += sred[t + s]; __syncthreads(); }
    if (t == 0) fn2[pb] = sred[0];
}

// ---------- sim: fused normalize + similarity + valid; also zeroes Ssum ----------
__global__ __launch_bounds__(128) void sim_kernel(
    const float* __restrict__ feature,
    const float* __restrict__ text_feature,
    float* __restrict__ img_sim,
    float* __restrict__ txt_sim,
    float* __restrict__ validf,
    float* __restrict__ Ssum) {
    const int p = blockIdx.x;
    const int b0 = blockIdx.y * 2;        // 2 rows per block
    const int c = threadIdx.x;            // 128 threads, one column each
    if (blockIdx.y == 0) Ssum[p * B_ + c] = 0.0f;   // zero accumulator for neg_mfma
    __shared__ float ai[2][D_];
    __shared__ float at[2][D_];
    __shared__ float cinv_i[128];
    __shared__ float cinv_t[128];
    __shared__ int flags[2];
    #pragma unroll
    for (int i = 0; i < 8; ++i) {
        int idx = c + i * 128;            // 0..1023
        int row = idx >> 9, d = idx & 511;
        ai[row][d] = feature[(size_t)(p * B_ + b0 + row) * D_ + d];
        at[row][d] = text_feature[((size_t)(b0 + row) * P_ + p) * D_ + d];
    }
    if (c < 2) flags[c] = 0;
    __syncthreads();
    float di[2] = {0, 0};
    float dt[2] = {0, 0};
    float ssi = 0.0f, sst = 0.0f;         // column sumsq (raw)
    const float* fc = feature + (size_t)(p * B_ + c) * D_;
    const float* tc = text_feature + ((size_t)c * P_ + p) * D_;
    for (int d = 0; d < D_; d += 4) {
        float4 vi = *(const float4*)(fc + d);
        float4 vt = *(const float4*)(tc + d);
        ssi += vi.x * vi.x + vi.y * vi.y + vi.z * vi.z + vi.w * vi.w;
        sst += vt.x * vt.x + vt.y * vt.y + vt.z * vt.z + vt.w * vt.w;
        #pragma unroll
        for (int i = 0; i < 2; ++i) {
            float4 a4 = *(const float4*)&ai[i][d];
            float4 t4 = *(const float4*)&at[i][d];
            di[i] += a4.x * vi.x + a4.y * vi.y + a4.z * vi.z + a4.w * vi.w;
            dt[i] += t4.x * vt.x + t4.y * vt.y + t4.z * vt.z + t4.w * vt.w;
        }
    }
    cinv_i[c] = 1.0f / fmaxf(sqrtf(ssi), 1e-12f);
    cinv_t[c] = 1.0f / fmaxf(sqrtf(sst), 1e-12f);
    __syncthreads();
    #pragma unroll
    for (int i = 0; i < 2; ++i) {
        float is = 2.0f * di[i] * cinv_i[b0 + i] * cinv_i[c];   // / TEMP (0.5)
        float ts = 2.0f * dt[i] * cinv_t[b0 + i] * cinv_t[c];
        img_sim[(size_t)(p * B_ + b0 + i) * B_ + c] = is;
        txt_sim[(size_t)(p * B_ + b0 + i) * B_ + c] = ts;
        if (is > 0.7f && ts > 0.7f) flags[i] = 1;   // benign write race
    }
    __syncthreads();
    if (c < 2) validf[p * B_ + b0 + c] = (float)flags[c];
}

// ---------- per-row masked log-softmax + symmetric KL (one wave per row) ----------
__global__ __launch_bounds__(256) void kl_kernel(
    const float* __restrict__ img_sim,
    const float* __restrict__ txt_sim,
    const float* __restrict__ validf,
    float* __restrict__ klrow) {
    const int l = threadIdx.x & 63;
    const int wv = threadIdx.x >> 6;
    const int p = blockIdx.x;
    const int r = blockIdx.y * 4 + wv;
    const size_t base = (size_t)(p * B_ + r) * B_;
    const bool v0 = validf[p * B_ + l] > 0.5f;
    const bool v1 = validf[p * B_ + 64 + l] > 0.5f;
    const float il0 = v0 ? img_sim[base + l] : -1e30f;
    const float il1 = v1 ? img_sim[base + 64 + l] : -1e30f;
    const float tl0 = v0 ? txt_sim[base + l] : -1e30f;
    const float tl1 = v1 ? txt_sim[base + 64 + l] : -1e30f;
    float mi = fmaxf(il0, il1), mt = fmaxf(tl0, tl1);
    #pragma unroll
    for (int off = 32; off > 0; off >>= 1) {
        mi = fmaxf(mi, __shfl_xor(mi, off));
        mt = fmaxf(mt, __shfl_xor(mt, off));
    }
    float si = expf(il0 - mi) + expf(il1 - mi);
    float st = expf(tl0 - mt) + expf(tl1 - mt);
    #pragma unroll
    for (int off = 32; off > 0; off >>= 1) {
        si += __shfl_xor(si, off);
        st += __shfl_xor(st, off);
    }
    const float lsei = mi + logf(si);
    const float lset = mt + logf(st);
    float term = 0.0f;
    if (v0) {
        float lpi = il0 - lsei, lpt = tl0 - lset;
        term += expf(lpt) * (lpt - lpi) + expf(lpi) * (lpi - lpt);
    }
    if (v1) {
        float lpi = il1 - lsei, lpt = tl1 - lset;
        term += expf(lpt) * (lpt - lpi) + expf(lpi) * (lpi - lpt);
    }
    #pragma unroll
    for (int off = 32; off > 0; off >>= 1) term += __shfl_xor(term, off);
    if (l == 0) klrow[p * B_ + r] = (validf[p * B_ + r] > 0.5f) ? term : 0.0f;
}

// ---------- x[p,b] = log sum_k exp(-SCALE * pos_dist); fn2 computed inline ----------
__global__ void posx_kernel(const float* __restrict__ feature,
                            const float* __restrict__ centers,
                            const int* __restrict__ cross,
                            float* __restrict__ xarr) {
    const int pb = blockIdx.x;
    const int p = pb >> 7, b = pb & 127;
    const int l = threadIdx.x;            // 64 (one wave)
    const float* f = feature + (size_t)pb * D_;
    float4 f0 = *(const float4*)(f + l * 4);
    float4 f1 = *(const float4*)(f + 256 + l * 4);
    float fs = f0.x * f0.x + f0.y * f0.y + f0.z * f0.z + f0.w * f0.w
             + f1.x * f1.x + f1.y * f1.y + f1.z * f1.z + f1.w * f1.w;
    #pragma unroll
    for (int off = 32; off > 0; off >>= 1) fs += __shfl_down(fs, off);
    // fs = ||f||^2 valid on lane 0
    float ex = 0.0f;
    #pragma unroll
    for (int k = 0; k < K_; ++k) {
        int idx = cross[b * K_ + k];
        const float* cp = centers + ((size_t)p * N_ + idx) * D_;
        float4 c0 = *(const float4*)(cp + l * 4);
        float4 c1 = *(const float4*)(cp + 256 + l * 4);
        float dot = f0.x * c0.x + f0.y * c0.y + f0.z * c0.z + f0.w * c0.w
                  + f1.x * c1.x + f1.y * c1.y + f1.z * c1.z + f1.w * c1.w;
        float pn2 = c0.x * c0.x + c0.y * c0.y + c0.z * c0.z + c0.w * c0.w
                  + c1.x * c1.x + c1.y * c1.y + c1.z * c1.z + c1.w * c1.w;
        #pragma unroll
        for (int off = 32; off > 0; off >>= 1) {
            dot += __shfl_down(dot, off);
            pn2 += __shfl_down(pn2, off);
        }
        if (l == 0) {
            float d2 = fs + pn2 - 2.0f * dot;
            ex += expf(-10.0f * sqrtf(fmaxf(d2, 1e-12f)));
        }
    }
    if (l == 0) xarr[pb] = logf(ex);
}

// ---------- main kernel v5: full-row contiguous staging, n-group pipeline ----------
// B (centers) is streamed in 4 groups of 32 FULL rows per block: every global
// staging instruction reads 128 B contiguous per row (full 64B lines), the
// proven 6+ TB/s access shape. Staged regs -> cvt bf16 + row sumsq (cn2) ->
// padded LDS [32][520] (stride 260 dwords = 4 mod 32: conflict-light b128).
// Per group: 16 K-chunks x {2 A-frag loads (bf16 global, full-line, L2-hot),
// 2 B ds_reads, 4 MFMA}; epilogue folds exp/mask into per-lane ssum registers.
// One non-draining barrier per group; staging vmcnt counted at the write.
__global__ __launch_bounds__(256) void neg_mfma_kernel(
    const unsigned short* __restrict__ Abf,
    const float* __restrict__ centers,
    const float* __restrict__ fn2,
    const int* __restrict__ cross,
    const int* __restrict__ position,
    float* __restrict__ Ssum) {
    const int tile = blockIdx.x;          // 0..NT2-1
    const int p = blockIdx.y;
    const int n0g = tile * TNB;
    const int t = threadIdx.x;
    const int l = t & 63;                 // lane
    const int w = t >> 6;                 // wave 0..3 (owns m-rows 32w..32w+31)
    const int fr = l & 15;                // frag row (operand) / col (C) within 16
    const int kg = l >> 4;                // k-group 0..3
    const int il = l & 7;                 // staging: float4-slot within row
    const int rw = l >> 3;                // staging: row-in-wave 0..7

    __shared__ unsigned short Bs[2][NG * BSTR];   // 2 x 33,280 B
    __shared__ float cn2g[2][NG];
    __shared__ float msk[128];

    // ---- mask setup ----
    if (t < 128) msk[t] = 1.0f;
    __syncthreads();
    for (int i = t; i < B_ * K_ + B_; i += 256) {
        const int v = (i < B_ * K_) ? cross[i] : position[i - B_ * K_];
        const unsigned rr = (unsigned)(v - n0g);
        if (rr < (unsigned)TNB) msk[rr] = 0.0f;
    }

    // staging row (within group) for this lane
    const int srow = w * 8 + rw;          // 0..31

    // load half h (h=0: float4s 0..63, h=1: 64..127) of group g's rows
#define STAGE_LOAD(g, h, vv) \
    { const float* rp = centers + ((size_t)p * N_ + n0g + (g) * NG + srow) * D_; \
      _Pragma("unroll") \
      for (int q = 0; q < 8; ++q) \
        vv[q] = *(const float4*)(rp + ((h) * 64 + q * 8 + il) * 4); }

    // cvt + write half h into Bs[buf]; accumulate row sumsq into s2
#define STAGE_WRITE(h, vv, buf, s2) \
    { _Pragma("unroll") \
      for (int q = 0; q < 8; ++q) { \
        s2 += vv[q].x * vv[q].x + vv[q].y * vv[q].y \
            + vv[q].z * vv[q].z + vv[q].w * vv[q].w; \
        *(uint2*)&Bs[buf][srow * BSTR + ((h) * 64 + q * 8 + il) * 4] = pack_bf16x4(vv[q]); \
      } }

#define STAGE_FIN(buf, s2) \
    { float s = s2; \
      s += __shfl_xor(s, 1); s += __shfl_xor(s, 2); s += __shfl_xor(s, 4); \
      if (il == 0) cn2g[buf][srow] = s; }

    // A-frag bases: wave's two 16-row m-frags, per-lane row fr, k-offset kg*8
    const unsigned short* Ap0 = Abf + ((size_t)p * B_ + w * 32 + fr) * D_ + kg * 8;
    const unsigned short* Ap1 = Ap0 + (size_t)16 * D_;

    // fn2 for this lane's C rows (m = w*32 + 16i + kg*4 + r)
    float fvv0[4], fvv1[4];
    #pragma unroll
    for (int r = 0; r < 4; ++r) {
        fvv0[r] = fn2[p * B_ + w * 32 + kg * 4 + r];
        fvv1[r] = fn2[p * B_ + w * 32 + 16 + kg * 4 + r];
    }

    f32x4 acc00, acc01, acc10, acc11;     // [i][j]: i = m-frag, j = n-frag
    float ssum0[4] = {0, 0, 0, 0};        // per-lane running exp-sums, i=0
    float ssum1[4] = {0, 0, 0, 0};        // i=1

    float4 vst[8];
    float s2a;

    // ---- prologue: stage group 0 ----
    s2a = 0.0f;
    STAGE_LOAD(0, 0, vst)
    STAGE_WRITE(0, vst, 0, s2a)
    STAGE_LOAD(0, 1, vst)
    STAGE_WRITE(1, vst, 0, s2a)
    STAGE_FIN(0, s2a)
    __syncthreads();                      // group 0 visible; msk scatter visible

#define COMPUTE_CHUNKS(buf, c0, c1) \
    _Pragma("unroll") \
    for (int c = (c0); c < (c1); ++c) { \
        bf16x8 a0 = *(const bf16x8*)(Ap0 + c * 32); \
        bf16x8 a1 = *(const bf16x8*)(Ap1 + c * 32); \
        bf16x8 b0 = *(const bf16x8*)&Bs[buf][fr * BSTR + kg * 8 + c * 32]; \
        bf16x8 b1 = *(const bf16x8*)&Bs[buf][(fr + 16) * BSTR + kg * 8 + c * 32]; \
        acc00 = __builtin_amdgcn_mfma_f32_16x16x32_bf16(a0, b0, acc00, 0, 0, 0); \
        acc01 = __builtin_amdgcn_mfma_f32_16x16x32_bf16(a0, b1, acc01, 0, 0, 0); \
        acc10 = __builtin_amdgcn_mfma_f32_16x16x32_bf16(a1, b0, acc10, 0, 0, 0); \
        acc11 = __builtin_amdgcn_mfma_f32_16x16x32_bf16(a1, b1, acc11, 0, 0, 0); \
    }

    for (int g = 0; g < NGR; ++g) {
        const int cur = g & 1, nxt = cur ^ 1;
        acc00 = (f32x4)0.0f; acc01 = (f32x4)0.0f;
        acc10 = (f32x4)0.0f; acc11 = (f32x4)0.0f;
        s2a = 0.0f;
        // issue next group's first-half loads early (latency hides under MFMA)
        if (g + 1 < NGR) STAGE_LOAD(g + 1, 0, vst)
        COMPUTE_CHUNKS(cur, 0, 8)
        if (g + 1 < NGR) {
            STAGE_WRITE(0, vst, nxt, s2a)         // counted vmcnt: waits own loads
            STAGE_LOAD(g + 1, 1, vst)
        }
        COMPUTE_CHUNKS(cur, 8, 16)
        if (g + 1 < NGR) {
            STAGE_WRITE(1, vst, nxt, s2a)
            STAGE_FIN(nxt, s2a)
        }
        // ---- group epilogue: fold exp/mask into per-lane running sums ----
        {
            const float c20 = cn2g[cur][fr];
            const float c21 = cn2g[cur][fr + 16];
            const float mk0 = msk[g * NG + fr];
            const float mk1 = msk[g * NG + 16 + fr];
            #pragma unroll
            for (int r = 0; r < 4; ++r) {
                float nd;
                nd = fvv0[r] + c20 - 2.0f * acc00[r];
                ssum0[r] += mk0 * __expf(-10.0f * sqrtf(fmaxf(nd, 1e-12f)));
                nd = fvv0[r] + c21 - 2.0f * acc01[r];
                ssum0[r] += mk1 * __expf(-10.0f * sqrtf(fmaxf(nd, 1e-12f)));
                nd = fvv1[r] + c20 - 2.0f * acc10[r];
                ssum1[r] += mk0 * __expf(-10.0f * sqrtf(fmaxf(nd, 1e-12f)));
                nd = fvv1[r] + c21 - 2.0f * acc11[r];
                ssum1[r] += mk1 * __expf(-10.0f * sqrtf(fmaxf(nd, 1e-12f)));
            }
        }
        // non-draining barrier: ds_writes visible, staged/global regs unaffected
        asm volatile("s_waitcnt lgkmcnt(0)\n\ts_barrier" ::: "memory");
    }

#undef STAGE_LOAD
#undef STAGE_WRITE
#undef STAGE_FIN
#undef COMPUTE_CHUNKS

    // ---- final: reduce ssum across the 16 fr-lanes; one atomic per row ----
    #pragma unroll
    for (int r = 0; r < 4; ++r) {
        float v0 = ssum0[r];
        v0 += __shfl_xor(v0, 1); v0 += __shfl_xor(v0, 2);
        v0 += __shfl_xor(v0, 4); v0 += __shfl_xor(v0, 8);
        if (fr == 0) atomicAdd(&Ssum[p * B_ + w * 32 + kg * 4 + r], v0);
        float v1 = ssum1[r];
        v1 += __shfl_xor(v1, 1); v1 += __shfl_xor(v1, 2);
        v1 += __shfl_xor(v1, 4); v1 += __shfl_xor(v1, 8);
        if (fr == 0) atomicAdd(&Ssum[p * B_ + w * 32 + 16 + kg * 4 + r], v1);
    }
}

// ---------- final scalars + pos_vid gather (diff computed inline from Ssum) ----------
__global__ void final_kernel(const float* __restrict__ validf,
                             const float* __restrict__ klrow,
                             const float* __restrict__ xarr,
                             const float* __restrict__ Ssum,
                             const int* __restrict__ cross,
                             const int* __restrict__ vid,
                             float* __restrict__ out) {
    const int t = threadIdx.x;            // 128
    __shared__ float sh[128];
    __shared__ float accum[2];            // [0]=contrastive sum over p, [1]=align
    if (t == 0) { accum[0] = 0.0f; accum[1] = 0.0f; }
    __syncthreads();
    for (int p = 0; p < P_; ++p) {
        float nv = block_sum_128(validf[p * B_ + t], sh);
        float ks = block_sum_128(klrow[p * B_ + t], sh);
        float dv = logf(Ssum[p * B_ + t]) - xarr[p * B_ + t];
        float ds = block_sum_128(dv, sh);
        if (t == 0) {
            float lp = ds / (float)B_;
            if (!(lp != lp)) accum[0] += lp;                    // where(isnan, 0)
            if (nv > 0.5f) accum[1] += 0.5f * ks / fmaxf(nv, 1.0f);
        }
        __syncthreads();
    }
    if (t == 0) {
        float contrastive = accum[0] / (float)P_;
        float align = accum[1];
        out[1] = contrastive;
        out[2] = align;
        // KL_WEIGHT = max(0.5*(1 - 1/60), 0.1)
        out[0] = contrastive + 0.49166666666666664f * align;
    }
    #pragma unroll
    for (int k = 0; k < K_; ++k) {
        const int i = k * 128 + t;        // 0..1279
        out[3 + i] = (float)vid[cross[i]];
    }
}

extern "C" void kernel_launch(void* const* d_in, const int* in_sizes, int n_in,
                              void* d_out, int out_size, void* d_ws, size_t ws_size,
                              hipStream_t stream) {
    const float* feature      = (const float*)d_in[0];
    const float* text_feature = (const float*)d_in[1];
    const float* centers      = (const float*)d_in[2];
    const int*   position     = (const int*)d_in[3];
    const int*   cross        = (const int*)d_in[4];
    const int*   vid          = (const int*)d_in[5];
    float* out = (float*)d_out;

    // workspace layout (floats)
    float* ws      = (float*)d_ws;
    float* img_sim = ws;                                  // P*B*B
    float* txt_sim = img_sim + (size_t)P_ * B_ * B_;      // P*B*B
    float* validf  = txt_sim + (size_t)P_ * B_ * B_;      // P*B
    float* klrow   = validf + P_ * B_;                    // P*B
    float* xarr    = klrow + P_ * B_;                     // P*B
    float* Ssum    = xarr + P_ * B_;                      // P*B
    float* fn2     = Ssum + P_ * B_;                      // P*B
    unsigned short* Abf = (unsigned short*)(fn2 + P_ * B_);  // P*B*D bf16

    prep_kernel<<<P_ * B_, 256, 0, stream>>>(feature, Abf, fn2);
    sim_kernel<<<dim3(P_, B_ / 2), 128, 0, stream>>>(feature, text_feature,
                                                     img_sim, txt_sim, validf, Ssum);
    kl_kernel<<<dim3(P_, B_ / 4), 256, 0, stream>>>(img_sim, txt_sim, validf, klrow);
    posx_kernel<<<P_ * B_, 64, 0, stream>>>(feature, centers, cross, xarr);
    neg_mfma_kernel<<<dim3(NT2, P_), 256, 0, stream>>>(Abf, centers, fn2, cross,
                                                       position, Ssum);
    final_kernel<<<1, 128, 0, stream>>>(validf, klrow, xarr, Ssum, cross, vid, out);
}

// Round 6
// 445.197 us; speedup vs baseline: 1.2354x; 1.2354x over previous
//
#include <hip/hip_runtime.h>
#include <hip/hip_bf16.h>
#include <math.h>

// Problem constants (from reference setup_inputs)
#define P_ 4
#define B_ 128
#define D_ 512
#define N_ 32768
#define K_ 10
#define TNB 128          // n-tile per block in neg_mfma_kernel
#define NT2 (N_ / TNB)   // 256 tiles per p
#define BK2 32           // k-chunk (1 MFMA K-step)
#define NCH (D_ / BK2)   // 16 chunks

typedef __attribute__((ext_vector_type(8))) short bf16x8;   // 8 bf16 (4 VGPRs)
typedef __attribute__((ext_vector_type(4))) float f32x4;    // MFMA acc

// direct HBM->LDS, 16B per lane, LDS dest = wave-uniform base + lane*16
#define GLD(g, l) __builtin_amdgcn_global_load_lds( \
    (const __attribute__((address_space(1))) void*)(g), \
    (__attribute__((address_space(3))) void*)(l), 16, 0, 0)

static __device__ __forceinline__ float block_sum_128(float v, float* sh) {
    const int t = threadIdx.x;
    sh[t] = v; __syncthreads();
    #pragma unroll
    for (int s = 64; s > 0; s >>= 1) { if (t < s) sh[t] += sh[t + s]; __syncthreads(); }
    float r = sh[0]; __syncthreads();
    return r;
}

static __device__ __forceinline__ unsigned cvt2bf(float a, float b) {
    union { __hip_bfloat162 h; unsigned u; } p;
    p.h = __float22bfloat162_rn(make_float2(a, b));   // RNE
    return p.u;
}

// ---------- prep: feature -> bf16 copy (for A staging) + fn2 ----------
__global__ __launch_bounds__(256) void prep_kernel(const float* __restrict__ feature,
                                                   unsigned short* __restrict__ Abf,
                                                   float* __restrict__ fn2) {
    const int pb = blockIdx.x;            // 0..P*B-1
    const int t = threadIdx.x;            // 256 threads, 2 consecutive elems each
    const float2 v = *(const float2*)(feature + (size_t)pb * D_ + 2 * t);
    ((unsigned*)Abf)[(size_t)pb * (D_ / 2) + t] = cvt2bf(v.x, v.y);
    __shared__ float sred[256];
    sred[t] = v.x * v.x + v.y * v.y;
    __syncthreads();
    #pragma unroll
    for (int s = 128; s > 0; s >>= 1) { if (t < s) sred[t] += sred[t + s]; __syncthreads(); }
    if (t == 0) fn2[pb] = sred[0];
}

// ---------- sim: fused normalize + similarity + valid; also zeroes Ssum ----------
__global__ __launch_bounds__(128) void sim_kernel(
    const float* __restrict__ feature,
    const float* __restrict__ text_feature,
    float* __restrict__ img_sim,
    float* __restrict__ txt_sim,
    float* __restrict__ validf,
    float* __restrict__ Ssum) {
    const int p = blockIdx.x;
    const int b0 = blockIdx.y * 2;        // 2 rows per block
    const int c = threadIdx.x;            // 128 threads, one column each
    if (blockIdx.y == 0) Ssum[p * B_ + c] = 0.0f;   // zero accumulator for neg_mfma
    __shared__ float ai[2][D_];
    __shared__ float at[2][D_];
    __shared__ float cinv_i[128];
    __shared__ float cinv_t[128];
    __shared__ int flags[2];
    #pragma unroll
    for (int i = 0; i < 8; ++i) {
        int idx = c + i * 128;            // 0..1023
        int row = idx >> 9, d = idx & 511;
        ai[row][d] = feature[(size_t)(p * B_ + b0 + row) * D_ + d];
        at[row][d] = text_feature[((size_t)(b0 + row) * P_ + p) * D_ + d];
    }
    if (c < 2) flags[c] = 0;
    __syncthreads();
    float di[2] = {0, 0};
    float dt[2] = {0, 0};
    float ssi = 0.0f, sst = 0.0f;         // column sumsq (raw)
    const float* fc = feature + (size_t)(p * B_ + c) * D_;
    const float* tc = text_feature + ((size_t)c * P_ + p) * D_;
    for (int d = 0; d < D_; d += 4) {
        float4 vi = *(const float4*)(fc + d);
        float4 vt = *(const float4*)(tc + d);
        ssi += vi.x * vi.x + vi.y * vi.y + vi.z * vi.z + vi.w * vi.w;
        sst += vt.x * vt.x + vt.y * vt.y + vt.z * vt.z + vt.w * vt.w;
        #pragma unroll
        for (int i = 0; i < 2; ++i) {
            float4 a4 = *(const float4*)&ai[i][d];
            float4 t4 = *(const float4*)&at[i][d];
            di[i] += a4.x * vi.x + a4.y * vi.y + a4.z * vi.z + a4.w * vi.w;
            dt[i] += t4.x * vt.x + t4.y * vt.y + t4.z * vt.z + t4.w * vt.w;
        }
    }
    cinv_i[c] = 1.0f / fmaxf(sqrtf(ssi), 1e-12f);
    cinv_t[c] = 1.0f / fmaxf(sqrtf(sst), 1e-12f);
    __syncthreads();
    #pragma unroll
    for (int i = 0; i < 2; ++i) {
        float is = 2.0f * di[i] * cinv_i[b0 + i] * cinv_i[c];   // / TEMP (0.5)
        float ts = 2.0f * dt[i] * cinv_t[b0 + i] * cinv_t[c];
        img_sim[(size_t)(p * B_ + b0 + i) * B_ + c] = is;
        txt_sim[(size_t)(p * B_ + b0 + i) * B_ + c] = ts;
        if (is > 0.7f && ts > 0.7f) flags[i] = 1;   // benign write race
    }
    __syncthreads();
    if (c < 2) validf[p * B_ + b0 + c] = (float)flags[c];
}

// ---------- per-row masked log-softmax + symmetric KL (one wave per row) ----------
__global__ __launch_bounds__(256) void kl_kernel(
    const float* __restrict__ img_sim,
    const float* __restrict__ txt_sim,
    const float* __restrict__ validf,
    float* __restrict__ klrow) {
    const int l = threadIdx.x & 63;
    const int wv = threadIdx.x >> 6;
    const int p = blockIdx.x;
    const int r = blockIdx.y * 4 + wv;
    const size_t base = (size_t)(p * B_ + r) * B_;
    const bool v0 = validf[p * B_ + l] > 0.5f;
    const bool v1 = validf[p * B_ + 64 + l] > 0.5f;
    const float il0 = v0 ? img_sim[base + l] : -1e30f;
    const float il1 = v1 ? img_sim[base + 64 + l] : -1e30f;
    const float tl0 = v0 ? txt_sim[base + l] : -1e30f;
    const float tl1 = v1 ? txt_sim[base + 64 + l] : -1e30f;
    float mi = fmaxf(il0, il1), mt = fmaxf(tl0, tl1);
    #pragma unroll
    for (int off = 32; off > 0; off >>= 1) {
        mi = fmaxf(mi, __shfl_xor(mi, off));
        mt = fmaxf(mt, __shfl_xor(mt, off));
    }
    float si = expf(il0 - mi) + expf(il1 - mi);
    float st = expf(tl0 - mt) + expf(tl1 - mt);
    #pragma unroll
    for (int off = 32; off > 0; off >>= 1) {
        si += __shfl_xor(si, off);
        st += __shfl_xor(st, off);
    }
    const float lsei = mi + logf(si);
    const float lset = mt + logf(st);
    float term = 0.0f;
    if (v0) {
        float lpi = il0 - lsei, lpt = tl0 - lset;
        term += expf(lpt) * (lpt - lpi) + expf(lpi) * (lpi - lpt);
    }
    if (v1) {
        float lpi = il1 - lsei, lpt = tl1 - lset;
        term += expf(lpt) * (lpt - lpi) + expf(lpi) * (lpi - lpt);
    }
    #pragma unroll
    for (int off = 32; off > 0; off >>= 1) term += __shfl_xor(term, off);
    if (l == 0) klrow[p * B_ + r] = (validf[p * B_ + r] > 0.5f) ? term : 0.0f;
}

// ---------- x[p,b] = log sum_k exp(-SCALE * pos_dist); fn2 computed inline ----------
__global__ void posx_kernel(const float* __restrict__ feature,
                            const float* __restrict__ centers,
                            const int* __restrict__ cross,
                            float* __restrict__ xarr) {
    const int pb = blockIdx.x;
    const int p = pb >> 7, b = pb & 127;
    const int l = threadIdx.x;            // 64 (one wave)
    const float* f = feature + (size_t)pb * D_;
    float4 f0 = *(const float4*)(f + l * 4);
    float4 f1 = *(const float4*)(f + 256 + l * 4);
    float fs = f0.x * f0.x + f0.y * f0.y + f0.z * f0.z + f0.w * f0.w
             + f1.x * f1.x + f1.y * f1.y + f1.z * f1.z + f1.w * f1.w;
    #pragma unroll
    for (int off = 32; off > 0; off >>= 1) fs += __shfl_down(fs, off);
    // fs = ||f||^2 valid on lane 0
    float ex = 0.0f;
    #pragma unroll
    for (int k = 0; k < K_; ++k) {
        int idx = cross[b * K_ + k];
        const float* cp = centers + ((size_t)p * N_ + idx) * D_;
        float4 c0 = *(const float4*)(cp + l * 4);
        float4 c1 = *(const float4*)(cp + 256 + l * 4);
        float dot = f0.x * c0.x + f0.y * c0.y + f0.z * c0.z + f0.w * c0.w
                  + f1.x * c1.x + f1.y * c1.y + f1.z * c1.z + f1.w * c1.w;
        float pn2 = c0.x * c0.x + c0.y * c0.y + c0.z * c0.z + c0.w * c0.w
                  + c1.x * c1.x + c1.y * c1.y + c1.z * c1.z + c1.w * c1.w;
        #pragma unroll
        for (int off = 32; off > 0; off >>= 1) {
            dot += __shfl_down(dot, off);
            pn2 += __shfl_down(pn2, off);
        }
        if (l == 0) {
            float d2 = fs + pn2 - 2.0f * dot;
            ex += expf(-10.0f * sqrtf(fmaxf(d2, 1e-12f)));
        }
    }
    if (l == 0) xarr[pb] = logf(ex);
}

// ---------- main kernel v7: global_load_lds + __syncthreads (m97 structure) ----------
// Same staging/swizzle as v6, but all loop sync is plain __syncthreads() —
// compiler drains vmcnt before s_barrier (safe, cannot hang). Pipeline: per
// chunk {STAGE(c+1 -> other buf); ds_read+cvt+MFMA on cur; barrier}. The
// drain waits next-chunk loads only after compute has elapsed; 3 blocks/CU
// (49 KB LDS) overlap the rest. Swizzle (both-sides, rule 21):
//   B LDS [128][8 slots of 16B]: staged slot l&7 <- global slot (l&7)^(row&7);
//     read slot (2kg)^(fr&7) => global slot 2kg. 8 lanes/slot = minimal for b128.
//   A LDS [128][4 slots]: staged slot l&3 <- global slot (l&3)^(row&3);
//     read slot kg^(fr&3) => global slot kg.
__global__ __launch_bounds__(256) void neg_mfma_kernel(
    const unsigned short* __restrict__ Abf,
    const float* __restrict__ centers,
    const float* __restrict__ fn2,
    const int* __restrict__ cross,
    const int* __restrict__ position,
    float* __restrict__ Ssum) {
    const int tile = blockIdx.x;          // 0..NT2-1
    const int p = blockIdx.y;
    const int n0g = tile * TNB;
    const int t = threadIdx.x;
    const int l = t & 63;                 // lane
    const int w = t >> 6;                 // wave 0..3
    const int m0w = (w & 1) * 64;         // wave m-offset (b rows)
    const int n0w = (w >> 1) * 64;        // wave n-offset
    const int fr = l & 15;                // frag row (operand) / col (C) within 16
    const int kg = l >> 4;                // k-group 0..3 (8 elems each)

    __shared__ float Bsf[2][128 * 32];            // f32 B chunk, 2 x 16 KB
    __shared__ unsigned short Ash[2][128 * 32];   // bf16 A chunk, 2 x 8 KB
    __shared__ float red[128];
    __shared__ float msk[128];
    __shared__ float fn2s[128];

    // ---- mask / red / fn2s setup ----
    if (t < 128) { red[t] = 0.0f; msk[t] = 1.0f; fn2s[t] = fn2[p * B_ + t]; }
    __syncthreads();
    for (int i = t; i < B_ * K_ + B_; i += 256) {
        const int v = (i < B_ * K_) ? cross[i] : position[i - B_ * K_];
        const unsigned rr = (unsigned)(v - n0g);
        if (rr < (unsigned)TNB) msk[rr] = 0.0f;
    }

    // staging geometry (per lane):
    //  B: instr q covers rows (w*4+q)*8 + (l>>3), LDS slot l&7, global slot swz
    //  A: instr q covers rows (w*2+q)*16 + (l>>2), LDS slot l&3, global slot swz
    const float* gB = centers + ((size_t)p * N_ + n0g + w * 32 + (l >> 3)) * D_
                    + ((l & 7) ^ (l >> 3)) * 4;
    const unsigned short* gA = Abf + ((size_t)p * B_ + w * 32 + (l >> 2)) * D_
                             + ((l & 3) ^ ((l >> 2) & 3)) * 8;

#define STAGE(cc, buf) { \
    _Pragma("unroll") \
    for (int q = 0; q < 4; ++q) \
        GLD(gB + (size_t)q * 8 * D_ + (cc) * 32, &Bsf[buf][(w * 4 + q) * 256]); \
    _Pragma("unroll") \
    for (int q = 0; q < 2; ++q) \
        GLD(gA + (size_t)q * 16 * D_ + (cc) * 32, &Ash[buf][(w * 2 + q) * 512]); \
  }

    f32x4 acc[4][4];
    #pragma unroll
    for (int i = 0; i < 4; ++i)
        #pragma unroll
        for (int j = 0; j < 4; ++j) acc[i][j] = (f32x4)0.0f;
    float cn2p[4] = {0.0f, 0.0f, 0.0f, 0.0f};

    const int akslot = kg ^ (fr & 3);         // A read slot (16B units)
    const int bslot0 = (2 * kg) ^ (fr & 7);   // B read slots (16B units)
    const int bslot1 = bslot0 ^ 1;

    // ---- prologue: stage chunk 0, wait it (barrier drains vmcnt) ----
    STAGE(0, 0)
    __syncthreads();

    #pragma unroll 1
    for (int c = 0; c < NCH; ++c) {
        const int cur = c & 1;
        // 1. issue next chunk's stage into the other buffer (in flight during compute)
        if (c + 1 < NCH) STAGE(c + 1, cur ^ 1)
        // 2. compute chunk c from buf[cur]
        bf16x8 af[4];
        #pragma unroll
        for (int i = 0; i < 4; ++i)
            af[i] = *(const bf16x8*)&Ash[cur][(m0w + i * 16 + fr) * 32 + akslot * 8];
        bf16x8 bfr[4];
        #pragma unroll
        for (int j = 0; j < 4; ++j) {
            const int row = n0w + j * 16 + fr;
            f32x4 lo = *(const f32x4*)&Bsf[cur][row * 32 + bslot0 * 4];
            f32x4 hi = *(const f32x4*)&Bsf[cur][row * 32 + bslot1 * 4];
            cn2p[j] += lo[0] * lo[0] + lo[1] * lo[1] + lo[2] * lo[2] + lo[3] * lo[3]
                     + hi[0] * hi[0] + hi[1] * hi[1] + hi[2] * hi[2] + hi[3] * hi[3];
            union { unsigned u[4]; bf16x8 v; } m;
            // un-swizzle: bslot0 holds global slot 2kg (lo half), bslot1 -> 2kg+1
            m.u[0] = cvt2bf(lo[0], lo[1]);
            m.u[1] = cvt2bf(lo[2], lo[3]);
            m.u[2] = cvt2bf(hi[0], hi[1]);
            m.u[3] = cvt2bf(hi[2], hi[3]);
            bfr[j] = m.v;
        }
        #pragma unroll
        for (int i = 0; i < 4; ++i)
            #pragma unroll
            for (int j = 0; j < 4; ++j)
                acc[i][j] = __builtin_amdgcn_mfma_f32_16x16x32_bf16(
                    af[i], bfr[j], acc[i][j], 0, 0, 0);
        // 3. barrier: drains vmcnt (next chunk staged) + lgkm (reads of cur done)
        __syncthreads();
    }
#undef STAGE

    // cn2: sum the 4 k-group slices (lane bits 4,5); each lane then holds the
    // full sumsq of row n0w + j*16 + fr -> exactly what the epilogue needs
    float c2l[4], mkl[4];
    #pragma unroll
    for (int j = 0; j < 4; ++j) {
        float s = cn2p[j];
        s += __shfl_xor(s, 16);
        s += __shfl_xor(s, 32);
        c2l[j] = s;
        mkl[j] = msk[n0w + j * 16 + fr];
    }

    // epilogue: C/D layout col=lane&15 (n), row=(lane>>4)*4+reg (b)  [m89/m91]
    #pragma unroll
    for (int i = 0; i < 4; ++i) {
        #pragma unroll
        for (int r = 0; r < 4; ++r) {
            const int row = m0w + i * 16 + kg * 4 + r;
            const float fv = fn2s[row];
            float s = 0.0f;
            #pragma unroll
            for (int j = 0; j < 4; ++j) {
                const float nd2 = fv + c2l[j] - 2.0f * acc[i][j][r];
                s += mkl[j] * __expf(-10.0f * sqrtf(fmaxf(nd2, 1e-12f)));
            }
            s += __shfl_xor(s, 1); s += __shfl_xor(s, 2);
            s += __shfl_xor(s, 4); s += __shfl_xor(s, 8);
            if (fr == 0) atomicAdd(&red[row], s);   // LDS atomic, 2 adds/row
        }
    }
    __syncthreads();
    if (t < 128) atomicAdd(&Ssum[p * B_ + t], red[t]);   // device-scope f32 add
}

// ---------- final scalars + pos_vid gather (diff computed inline from Ssum) ----------
__global__ void final_kernel(const float* __restrict__ validf,
                             const float* __restrict__ klrow,
                             const float* __restrict__ xarr,
                             const float* __restrict__ Ssum,
                             const int* __restrict__ cross,
                             const int* __restrict__ vid,
                             float* __restrict__ out) {
    const int t = threadIdx.x;            // 128
    __shared__ float sh[128];
    __shared__ float accum[2];            // [0]=contrastive sum over p, [1]=align
    if (t == 0) { accum[0] = 0.0f; accum[1] = 0.0f; }
    __syncthreads();
    for (int p = 0; p < P_; ++p) {
        float nv = block_sum_128(validf[p * B_ + t], sh);
        float ks = block_sum_128(klrow[p * B_ + t], sh);
        float dv = logf(Ssum[p * B_ + t]) - xarr[p * B_ + t];
        float ds = block_sum_128(dv, sh);
        if (t == 0) {
            float lp = ds / (float)B_;
            if (!(lp != lp)) accum[0] += lp;                    // where(isnan, 0)
            if (nv > 0.5f) accum[1] += 0.5f * ks / fmaxf(nv, 1.0f);
        }
        __syncthreads();
    }
    if (t == 0) {
        float contrastive = accum[0] / (float)P_;
        float align = accum[1];
        out[1] = contrastive;
        out[2] = align;
        // KL_WEIGHT = max(0.5*(1 - 1/60), 0.1)
        out[0] = contrastive + 0.49166666666666664f * align;
    }
    #pragma unroll
    for (int k = 0; k < K_; ++k) {
        const int i = k * 128 + t;        // 0..1279
        out[3 + i] = (float)vid[cross[i]];
    }
}

extern "C" void kernel_launch(void* const* d_in, const int* in_sizes, int n_in,
                              void* d_out, int out_size, void* d_ws, size_t ws_size,
                              hipStream_t stream) {
    const float* feature      = (const float*)d_in[0];
    const float* text_feature = (const float*)d_in[1];
    const float* centers      = (const float*)d_in[2];
    const int*   position     = (const int*)d_in[3];
    const int*   cross        = (const int*)d_in[4];
    const int*   vid          = (const int*)d_in[5];
    float* out = (float*)d_out;

    // workspace layout (floats)
    float* ws      = (float*)d_ws;
    float* img_sim = ws;                                  // P*B*B
    float* txt_sim = img_sim + (size_t)P_ * B_ * B_;      // P*B*B
    float* validf  = txt_sim + (size_t)P_ * B_ * B_;      // P*B
    float* klrow   = validf + P_ * B_;                    // P*B
    float* xarr    = klrow + P_ * B_;                     // P*B
    float* Ssum    = xarr + P_ * B_;                      // P*B
    float* fn2     = Ssum + P_ * B_;                      // P*B
    unsigned short* Abf = (unsigned short*)(fn2 + P_ * B_);  // P*B*D bf16

    prep_kernel<<<P_ * B_, 256, 0, stream>>>(feature, Abf, fn2);
    sim_kernel<<<dim3(P_, B_ / 2), 128, 0, stream>>>(feature, text_feature,
                                                     img_sim, txt_sim, validf, Ssum);
    kl_kernel<<<dim3(P_, B_ / 4), 256, 0, stream>>>(img_sim, txt_sim, validf, klrow);
    posx_kernel<<<P_ * B_, 64, 0, stream>>>(feature, centers, cross, xarr);
    neg_mfma_kernel<<<dim3(NT2, P_), 256, 0, stream>>>(Abf, centers, fn2, cross,
                                                       position, Ssum);
    final_kernel<<<1, 128, 0, stream>>>(validf, klrow, xarr, Ssum, cross, vid, out);
}